// Round 6
// baseline (454.963 us; speedup 1.0000x reference)
//
#include <hip/hip_runtime.h>
#include <hip/hip_bf16.h>

#define N_   32
#define C_   2048
#define ST_  16
#define H_   64      // ST*ALPHA
#define K_   3
#define CB_  512
#define LT_  400
#define LTP_ 402     // padded t rows (1 zero row each side)
#define BK   32      // K-step (bf16 elements) -> 64B LDS rows
#define TV1  254     // gemm1 valid rows per 256-row M tile (2-row tap halo)
#define FNT  12800   // N_*LT_ flattened (n,t) rows
#define JW   126     // gemm2 valid cols per 128-col N tile (2-col conv halo)

using bf16x8 = __attribute__((ext_vector_type(8))) __bf16;
using f32x4  = __attribute__((ext_vector_type(4))) float;
typedef unsigned short ushort_t;

__device__ __forceinline__ unsigned short f2bf(float f) {
    unsigned int u = __float_as_uint(f);
    u = (u + 0x7fffu + ((u >> 16) & 1u)) >> 16;
    return (unsigned short)u;
}
__device__ __forceinline__ float bf2f(unsigned short h) {
    return __uint_as_float(((unsigned int)h) << 16);
}
// async global->LDS DMA, 16B/lane. Dest = wave-uniform base + lane*16 (linear).
__device__ __forceinline__ void gload16(const ushort_t* g, ushort_t* l) {
    __builtin_amdgcn_global_load_lds(
        (const __attribute__((address_space(1))) unsigned int*)g,
        (__attribute__((address_space(3))) unsigned int*)l, 16, 0, 0);
}

// ---------------- P0: global branch -> per-(n,c) softmax kernel [NC,4] fp32
__global__ __launch_bounds__(256) void k_global(
    const float* __restrict__ st, const float* __restrict__ g_w1,
    const float* __restrict__ gam, const float* __restrict__ bet,
    const float* __restrict__ mean, const float* __restrict__ var,
    const float* __restrict__ g_w2, float* __restrict__ kern) {
    __shared__ float w1[H_][ST_];
    __shared__ float sc[H_], bi[H_];
    __shared__ float w2[K_][H_];
    int tid = threadIdx.x;
    for (int i = tid; i < H_ * ST_; i += 256) w1[i / ST_][i % ST_] = g_w1[i];
    if (tid < H_) {
        float s = gam[tid] * rsqrtf(var[tid] + 1e-5f);
        sc[tid] = s;
        bi[tid] = bet[tid] - mean[tid] * s;
    }
    for (int i = tid; i < K_ * H_; i += 256) w2[i / H_][i % H_] = g_w2[i];
    __syncthreads();
    int row = blockIdx.x * 256 + tid;  // n*C + c
    const float* p = st + (size_t)row * ST_;
    float s[ST_];
#pragma unroll
    for (int i = 0; i < ST_; ++i) s[i] = p[i];
    float lg0 = 0.f, lg1 = 0.f, lg2 = 0.f;
    for (int j = 0; j < H_; ++j) {
        float h = 0.f;
#pragma unroll
        for (int i = 0; i < ST_; ++i) h = fmaf(w1[j][i], s[i], h);
        h = fmaxf(fmaf(h, sc[j], bi[j]), 0.f);
        lg0 = fmaf(w2[0][j], h, lg0);
        lg1 = fmaf(w2[1][j], h, lg1);
        lg2 = fmaf(w2[2][j], h, lg2);
    }
    float m = fmaxf(lg0, fmaxf(lg1, lg2));
    float e0 = __expf(lg0 - m), e1 = __expf(lg1 - m), e2 = __expf(lg2 - m);
    float inv = 1.f / (e0 + e1 + e2);
    float4 o = make_float4(e0 * inv, e1 * inv, e2 * inv, 0.f);
    *(float4*)(kern + (size_t)row * 4) = o;
}

// ---------------- P1: transpose lt [n][c][t] fp32 -> ltT [n][t+1][c] bf16
__global__ __launch_bounds__(256) void k_transpose(
    const float* __restrict__ lt, ushort_t* __restrict__ ltT) {
    __shared__ float tile[32][33];
    int tt0 = blockIdx.x * 32;
    int cc  = blockIdx.y * 32;
    int n   = blockIdx.z;
    const float* src = lt + ((size_t)n * C_ + cc) * LT_;
    int tx = threadIdx.x & 31, ty = threadIdx.x >> 5;  // ty 0..7
#pragma unroll
    for (int i = 0; i < 4; ++i) {
        int c = ty + i * 8;
        int t = tt0 + tx;
        tile[c][tx] = (t < LT_) ? src[(size_t)c * LT_ + t] : 0.f;
    }
    __syncthreads();
    int cx  = (threadIdx.x & 15) * 2;   // c pair
    int tyw = threadIdx.x >> 4;         // 0..15
    unsigned int* dst = (unsigned int*)(ltT + (size_t)n * LTP_ * C_ + cc + cx);
#pragma unroll
    for (int i = 0; i < 2; ++i) {
        int tl = tyw + i * 16;
        int t = tt0 + tl;
        if (t < LT_) {
            unsigned int v = (unsigned int)f2bf(tile[cx][tl]) |
                             ((unsigned int)f2bf(tile[cx + 1][tl]) << 16);
            dst[(size_t)(t + 1) * (C_ / 2)] = v;
        }
    }
}

// zero the two pad rows of ltT
__global__ __launch_bounds__(256) void k_zero(ushort_t* __restrict__ ltT) {
    int i = blockIdx.x * 256 + threadIdx.x;  // over N*C
    int n = i >> 11, c = i & (C_ - 1);
    size_t base = (size_t)n * LTP_ * C_;
    ltT[base + c] = 0;
    ltT[base + (size_t)(LTP_ - 1) * C_ + c] = 0;
}

// ---------------- P2: repack l_w1 [cb][c][k] -> w1b[k][cb][c] bf16
__global__ __launch_bounds__(256) void k_w1(
    const float* __restrict__ l_w1, ushort_t* __restrict__ w1b) {
    int i = blockIdx.x * 256 + threadIdx.x;  // over CB*C
    float a = l_w1[(size_t)i * 3 + 0];
    float b = l_w1[(size_t)i * 3 + 1];
    float c = l_w1[(size_t)i * 3 + 2];
    w1b[0 * (size_t)CB_ * C_ + i] = f2bf(a);
    w1b[1 * (size_t)CB_ * C_ + i] = f2bf(b);
    w1b[2 * (size_t)CB_ * C_ + i] = f2bf(c);
}

// ---------------- P3: convert l_w2 [c][cb] -> bf16
__global__ __launch_bounds__(256) void k_w2(
    const float* __restrict__ l_w2, ushort_t* __restrict__ w2b) {
    int i = blockIdx.x * 256 + threadIdx.x;  // over C*CB
    w2b[i] = f2bf(l_w2[i]);
}

// ---------------- G1: X[n][t][cb] = ReLU(BN(sum_k W1k @ lt_shift_k)), bf16 out
// Round-3-proven structure (best of 3 tested schedules): 256x128 tile (254
// valid M rows), 8 waves (4M x 2N), 3-deep counted-vmcnt pipeline, monolithic
// MFMA body, XOR-swizzled LDS (linear DMA dest + pre-swizzled global source).
__global__ __launch_bounds__(512, 2) void k_gemm1(
    const ushort_t* __restrict__ ltT, const ushort_t* __restrict__ w1b,
    const float* __restrict__ bn_g, const float* __restrict__ bn_b,
    const float* __restrict__ bn_m, const float* __restrict__ bn_v,
    ushort_t* __restrict__ Xws) {
    __shared__ __align__(16) ushort_t Asm[3 * 256 * BK + 2 * BK];  // +2-row tap slack
    __shared__ __align__(16) ushort_t Bsm[3 * 384 * BK];
    const int tid = threadIdx.x;
    const int mseg = blockIdx.x;          // 0..63 = n*2 + tchunk
    const int n   = mseg >> 1;
    const int tm  = (mseg & 1) * TV1;     // 0 or 254 (padded-coord base row)
    const int cb0 = blockIdx.y * 128;
    const int lane = tid & 63, lrow = lane & 15, quad = lane >> 4;
    const int wv = tid >> 6;              // 0..7
    const int wvM = wv >> 1, wvN = wv & 1;

    const int srow = lane >> 2;
    const int csrc = (((lane & 3) ^ ((lane >> 3) & 3)) << 3);  // ushort offset
    const ushort_t* gA[2];
#pragma unroll
    for (int i = 0; i < 2; ++i) {
        int r = (2 * wv + i) * 16 + srow;                 // LDS row 0..255
        int gr = tm + r; gr = gr < LTP_ - 1 ? gr : LTP_ - 1;  // clamp to zero pad row
        gA[i] = ltT + ((size_t)n * LTP_ + gr) * C_ + csrc;
    }
    const ushort_t* gB[3];
#pragma unroll
    for (int j = 0; j < 3; ++j) {
        int rB = (3 * wv + j) * 16 + srow;                // LDS row 0..383 = tap*128+cbl
        gB[j] = w1b + ((size_t)((rB >> 7) * CB_ + cb0 + (rB & 127))) * C_ + csrc;
    }
    const int sB = lrow * BK + ((quad ^ ((lrow >> 1) & 3)) << 3);
    int sA[3];
#pragma unroll
    for (int k = 0; k < 3; ++k)
        sA[k] = (lrow + k) * BK + ((quad ^ (((lrow + k) >> 1) & 3)) << 3);

    f32x4 acc[4][4];
#pragma unroll
    for (int i = 0; i < 4; ++i)
#pragma unroll
        for (int j = 0; j < 4; ++j) acc[i][j] = (f32x4){0.f, 0.f, 0.f, 0.f};

#define STAGE1(buf)                                                         \
    {                                                                       \
        ushort_t* ad = Asm + (buf) * (256 * BK) + (2 * wv) * (16 * BK);     \
        gload16(gA[0], ad);                                                 \
        gload16(gA[1], ad + 16 * BK);                                       \
        gA[0] += BK; gA[1] += BK;                                           \
        ushort_t* bd = Bsm + (buf) * (384 * BK) + (3 * wv) * (16 * BK);     \
        gload16(gB[0], bd);                                                 \
        gload16(gB[1], bd + 16 * BK);                                       \
        gload16(gB[2], bd + 32 * BK);                                       \
        gB[0] += BK; gB[1] += BK; gB[2] += BK;                              \
    }

    STAGE1(0);
    STAGE1(1);
    int cur = 0, pre = 2;
    for (int s = 0; s < C_ / BK; ++s) {
        if (s < C_ / BK - 1) asm volatile("s_waitcnt vmcnt(5)" ::: "memory");
        else                 asm volatile("s_waitcnt vmcnt(0)" ::: "memory");
        __builtin_amdgcn_sched_barrier(0);
        __builtin_amdgcn_s_barrier();
        __builtin_amdgcn_sched_barrier(0);
        if (s < C_ / BK - 2) {
            STAGE1(pre);
            pre = (pre == 2) ? 0 : pre + 1;
        }
        const ushort_t* Ab = Asm + cur * (256 * BK) + wvM * (64 * BK);
        const ushort_t* Bb = Bsm + cur * (384 * BK) + wvN * (64 * BK) + sB;
        bf16x8 bfr[3][4];
#pragma unroll
        for (int k = 0; k < 3; ++k)
#pragma unroll
            for (int nf = 0; nf < 4; ++nf)
                bfr[k][nf] = *(const bf16x8*)(Bb + k * (128 * BK) + nf * (16 * BK));
        __builtin_amdgcn_s_setprio(1);
#pragma unroll
        for (int mf = 0; mf < 4; ++mf) {
            bf16x8 af[3];
#pragma unroll
            for (int k = 0; k < 3; ++k)
                af[k] = *(const bf16x8*)(Ab + sA[k] + mf * (16 * BK));
#pragma unroll
            for (int nf = 0; nf < 4; ++nf)
#pragma unroll
                for (int k = 0; k < 3; ++k)
                    acc[mf][nf] = __builtin_amdgcn_mfma_f32_16x16x32_bf16(af[k], bfr[k][nf], acc[mf][nf], 0, 0, 0);
        }
        __builtin_amdgcn_s_setprio(0);
        cur = (cur == 2) ? 0 : cur + 1;
    }
#undef STAGE1
    float sc[4], bo[4];
#pragma unroll
    for (int nf = 0; nf < 4; ++nf) {
        int cb = cb0 + wvN * 64 + nf * 16 + lrow;
        float s0 = bn_g[cb] * rsqrtf(bn_v[cb] + 1e-5f);
        sc[nf] = s0;
        bo[nf] = bn_b[cb] - bn_m[cb] * s0;
    }
#pragma unroll
    for (int mf = 0; mf < 4; ++mf) {
#pragma unroll
        for (int r = 0; r < 4; ++r) {
            int local = wvM * 64 + mf * 16 + quad * 4 + r;
            int t = tm + local;
            if (local < TV1 && t < LT_) {
#pragma unroll
                for (int nf = 0; nf < 4; ++nf) {
                    int cb = cb0 + wvN * 64 + nf * 16 + lrow;
                    float v = fmaxf(fmaf(acc[mf][nf][r], sc[nf], bo[nf]), 0.f);
                    Xws[((size_t)n * LT_ + t) * CB_ + cb] = f2bf(v);
                }
            }
        }
    }
}

// ---------------- G2 (FUSED FINAL): out[n][c][t] = sum_i kern[i]*(lt*sigmoid(W2@X))[t+i-1]
// M=c (128), N=128 flattened (n,t) cols with stride 126: cols 0 and 127 are
// conv halos (computed, not written) so no cross-tile data is needed. Neighbor
// nl values move via full-wave shfl (+1 KB LDS for the wvN seam). n-boundary
// zero-padding = masking taps by t==0 / t==LT-1. k_final is deleted.
__global__ __launch_bounds__(256, 3) void k_gemm2(
    const ushort_t* __restrict__ Xws, const ushort_t* __restrict__ w2b,
    const float* __restrict__ lt, const float* __restrict__ kern,
    float* __restrict__ out) {
    __shared__ __align__(16) ushort_t Asm[3 * 128 * BK];   // 24 KB
    __shared__ __align__(16) ushort_t Bsm[3 * 128 * BK];   // 24 KB
    __shared__ float nbnd[128][2];                          // seam nl: [c_local][j=63|j=64]
    const int tid = threadIdx.x;
    const int cm  = blockIdx.x * 128;
    const int fnBase = (int)blockIdx.y * JW - 1;  // col j -> flat row fnBase+j
    const int lane = tid & 63, lrow = lane & 15, quad = lane >> 4;
    const int wv = tid >> 6, wvM = wv & 1, wvN = wv >> 1;

    const int srow = lane >> 2;
    const int csrc = (((lane & 3) ^ ((lane >> 3) & 3)) << 3);
    const ushort_t* gA[2];
    const ushort_t* gB[2];
#pragma unroll
    for (int i = 0; i < 2; ++i) {
        int r = (2 * wv + i) * 16 + srow;
        gA[i] = w2b + (size_t)(cm + r) * CB_ + csrc;
        int fr = fnBase + r;                       // clamp halo/OOB rows (values
        fr = fr < 0 ? 0 : (fr > FNT - 1 ? FNT - 1 : fr);  // only used where masked)
        gB[i] = Xws + (size_t)fr * CB_ + csrc;
    }
    const int sOff = lrow * BK + ((quad ^ ((lrow >> 1) & 3)) << 3);

    f32x4 acc[4][4];
#pragma unroll
    for (int i = 0; i < 4; ++i)
#pragma unroll
        for (int j = 0; j < 4; ++j) acc[i][j] = (f32x4){0.f, 0.f, 0.f, 0.f};

#define STAGE2(buf)                                                         \
    {                                                                       \
        ushort_t* ad = Asm + (buf) * (128 * BK) + (2 * wv) * (16 * BK);     \
        ushort_t* bd = Bsm + (buf) * (128 * BK) + (2 * wv) * (16 * BK);     \
        gload16(gA[0], ad);                                                 \
        gload16(gA[1], ad + 16 * BK);                                       \
        gload16(gB[0], bd);                                                 \
        gload16(gB[1], bd + 16 * BK);                                       \
        gA[0] += BK; gA[1] += BK; gB[0] += BK; gB[1] += BK;                 \
    }

    STAGE2(0);
    STAGE2(1);
    int cur = 0, pre = 2;
    for (int s = 0; s < CB_ / BK; ++s) {
        if (s < CB_ / BK - 1) asm volatile("s_waitcnt vmcnt(4)" ::: "memory");
        else                  asm volatile("s_waitcnt vmcnt(0)" ::: "memory");
        __builtin_amdgcn_sched_barrier(0);
        __builtin_amdgcn_s_barrier();
        __builtin_amdgcn_sched_barrier(0);
        if (s < CB_ / BK - 2) {
            STAGE2(pre);
            pre = (pre == 2) ? 0 : pre + 1;
        }
        const ushort_t* Ab = Asm + cur * (128 * BK) + wvM * (64 * BK) + sOff;
        const ushort_t* Bb = Bsm + cur * (128 * BK) + wvN * (64 * BK) + sOff;
        bf16x8 af[4], bfm[4];
#pragma unroll
        for (int mf = 0; mf < 4; ++mf)
            af[mf] = *(const bf16x8*)(Ab + mf * (16 * BK));
#pragma unroll
        for (int nf = 0; nf < 4; ++nf)
            bfm[nf] = *(const bf16x8*)(Bb + nf * (16 * BK));
        __builtin_amdgcn_s_setprio(1);
#pragma unroll
        for (int mf = 0; mf < 4; ++mf)
#pragma unroll
            for (int nf = 0; nf < 4; ++nf)
                acc[mf][nf] = __builtin_amdgcn_mfma_f32_16x16x32_bf16(af[mf], bfm[nf], acc[mf][nf], 0, 0, 0);
        __builtin_amdgcn_s_setprio(0);
        cur = (cur == 2) ? 0 : cur + 1;
    }
#undef STAGE2
    // ---- fused epilogue: per mf-block {nl = lt*sigmoid(acc); seam store;
    //      barrier; conv3 via shfl; masked store} ----
#pragma unroll
    for (int mf = 0; mf < 4; ++mf) {
        int cl = wvM * 64 + mf * 16 + quad * 4;  // +r
        int c4 = cm + cl;
        f32x4 nlv[4];
#pragma unroll
        for (int nf = 0; nf < 4; ++nf) {
            int j  = wvN * 64 + nf * 16 + lrow;
            int fn = fnBase + j;
            int fnc = fn < 0 ? 0 : (fn > FNT - 1 ? FNT - 1 : fn);
            int nn = fnc / LT_, t = fnc - nn * LT_;
            const float* ltp = lt + ((size_t)nn * C_ + c4) * LT_ + t;
#pragma unroll
            for (int r = 0; r < 4; ++r) {
                float g = 1.f / (1.f + __expf(-acc[mf][nf][r]));
                nlv[nf][r] = ltp[(size_t)r * LT_] * g;
            }
        }
        // seam exchange across wvN (j=63 <-> j=64)
        if (wvN == 0 && lrow == 15) {
#pragma unroll
            for (int r = 0; r < 4; ++r) nbnd[cl + r][0] = nlv[3][r];
        }
        if (wvN == 1 && lrow == 0) {
#pragma unroll
            for (int r = 0; r < 4; ++r) nbnd[cl + r][1] = nlv[0][r];
        }
        __syncthreads();
#pragma unroll
        for (int r = 0; r < 4; ++r) {
            int c = c4 + r;
            float v0 = nlv[0][r], v1 = nlv[1][r], v2 = nlv[2][r], v3 = nlv[3][r];
            // j+1 (all shfls full-wave; selects applied after)
            float u0 = __shfl(v0, lane + 1, 64), x1 = __shfl(v1, lane - 15, 64);
            float u1 = __shfl(v1, lane + 1, 64), x2 = __shfl(v2, lane - 15, 64);
            float u2 = __shfl(v2, lane + 1, 64), x3 = __shfl(v3, lane - 15, 64);
            float u3 = __shfl(v3, lane + 1, 64);
            float r0 = (lrow < 15) ? u0 : x1;
            float r1 = (lrow < 15) ? u1 : x2;
            float r2 = (lrow < 15) ? u2 : x3;
            float r3 = (lrow < 15) ? u3 : ((wvN == 0) ? nbnd[cl + r][1] : 0.f);
            // j-1
            float d0 = __shfl(v0, lane - 1, 64), y0 = __shfl(v0, lane + 15, 64);
            float d1 = __shfl(v1, lane - 1, 64), y1 = __shfl(v1, lane + 15, 64);
            float d2 = __shfl(v2, lane - 1, 64), y2 = __shfl(v2, lane + 15, 64);
            float d3 = __shfl(v3, lane - 1, 64);
            float l0 = (lrow > 0) ? d0 : ((wvN == 1) ? nbnd[cl + r][0] : 0.f);
            float l1 = (lrow > 0) ? d1 : y0;
            float l2 = (lrow > 0) ? d2 : y1;
            float l3 = (lrow > 0) ? d3 : y2;
            float ctr[4] = {v0, v1, v2, v3};
            float lft[4] = {l0, l1, l2, l3};
            float rgt[4] = {r0, r1, r2, r3};
#pragma unroll
            for (int nf = 0; nf < 4; ++nf) {
                int j  = wvN * 64 + nf * 16 + lrow;
                int fn = fnBase + j;
                if (j >= 1 && j <= JW && fn < FNT) {
                    int nn = fn / LT_, t = fn - nn * LT_;
                    float4 kv = *(const float4*)(kern + ((size_t)nn * C_ + c) * 4);
                    float o = kv.y * ctr[nf];
                    if (t > 0)       o += kv.x * lft[nf];
                    if (t < LT_ - 1) o += kv.z * rgt[nf];
                    out[((size_t)nn * C_ + c) * LT_ + t] = o;
                }
            }
        }
        __syncthreads();   // nbnd reused next mf (distinct cl, but keep ordering safe)
    }
}

extern "C" void kernel_launch(void* const* d_in, const int* in_sizes, int n_in,
                              void* d_out, int out_size, void* d_ws, size_t ws_size,
                              hipStream_t stream) {
    const float* st   = (const float*)d_in[0];
    const float* lt   = (const float*)d_in[1];
    const float* g_w1 = (const float*)d_in[2];
    const float* g_bg = (const float*)d_in[3];
    const float* g_bb = (const float*)d_in[4];
    const float* g_bm = (const float*)d_in[5];
    const float* g_bv = (const float*)d_in[6];
    const float* g_w2 = (const float*)d_in[7];
    const float* l_w1 = (const float*)d_in[8];
    const float* l_bg = (const float*)d_in[9];
    const float* l_bb = (const float*)d_in[10];
    const float* l_bm = (const float*)d_in[11];
    const float* l_bv = (const float*)d_in[12];
    const float* l_w2 = (const float*)d_in[13];
    float* out = (float*)d_out;

    char* ws = (char*)d_ws;
    // workspace layout (bytes)
    float*    kern = (float*)(ws + 0);                    // 1,048,576
    ushort_t* w1b  = (ushort_t*)(ws + 1048576);           // 6,291,456
    ushort_t* w2b  = (ushort_t*)(ws + 7340032);           // 2,097,152
    ushort_t* Xws  = (ushort_t*)(ws + 9437184);           // 13,107,200
    ushort_t* ltT  = (ushort_t*)(ws + 22544384);          // 52,690,944

    k_global<<<dim3((N_ * C_) / 256), dim3(256), 0, stream>>>(
        st, g_w1, g_bg, g_bb, g_bm, g_bv, g_w2, kern);
    k_w1<<<dim3((CB_ * C_) / 256), dim3(256), 0, stream>>>(l_w1, w1b);
    k_w2<<<dim3((C_ * CB_) / 256), dim3(256), 0, stream>>>(l_w2, w2b);
    k_zero<<<dim3((N_ * C_) / 256), dim3(256), 0, stream>>>(ltT);
    k_transpose<<<dim3(13, C_ / 32, N_), dim3(256), 0, stream>>>(lt, ltT);
    k_gemm1<<<dim3(64, 4), dim3(512), 0, stream>>>(
        ltT, w1b, l_bg, l_bb, l_bm, l_bv, Xws);
    k_gemm2<<<dim3(C_ / 128, (FNT + JW - 1) / JW), dim3(256), 0, stream>>>(
        Xws, w2b, lt, kern, out);
}

// Round 7
// 442.943 us; speedup vs baseline: 1.0271x; 1.0271x over previous
//
#include <hip/hip_runtime.h>
#include <hip/hip_bf16.h>

#define N_   32
#define C_   2048
#define ST_  16
#define H_   64      // ST*ALPHA
#define K_   3
#define CB_  512
#define LT_  400
#define LTP_ 402     // padded t rows (1 zero row each side)
#define BK   32      // K-step (bf16 elements) -> 64B LDS rows
#define TV1  254     // gemm1 valid rows per 256-row M tile (2-row tap halo)
#define FNT  12800   // N_*LT_ flattened (n,t) rows
#define JW   126     // gemm2 valid cols per 128-col N tile (2-col conv halo)
#define NLD  132     // nl LDS row stride (bf16): pad 4 keeps 8B align + kills conflicts

using bf16x8 = __attribute__((ext_vector_type(8))) __bf16;
using f32x4  = __attribute__((ext_vector_type(4))) float;
typedef unsigned short ushort_t;

__device__ __forceinline__ unsigned short f2bf(float f) {
    unsigned int u = __float_as_uint(f);
    u = (u + 0x7fffu + ((u >> 16) & 1u)) >> 16;
    return (unsigned short)u;
}
__device__ __forceinline__ float bf2f(unsigned short h) {
    return __uint_as_float(((unsigned int)h) << 16);
}
// async global->LDS DMA, 16B/lane. Dest = wave-uniform base + lane*16 (linear).
__device__ __forceinline__ void gload16(const ushort_t* g, ushort_t* l) {
    __builtin_amdgcn_global_load_lds(
        (const __attribute__((address_space(1))) unsigned int*)g,
        (__attribute__((address_space(3))) unsigned int*)l, 16, 0, 0);
}

// ---------------- P0: global branch -> per-(n,c) softmax kernel [NC,4] fp32
__global__ __launch_bounds__(256) void k_global(
    const float* __restrict__ st, const float* __restrict__ g_w1,
    const float* __restrict__ gam, const float* __restrict__ bet,
    const float* __restrict__ mean, const float* __restrict__ var,
    const float* __restrict__ g_w2, float* __restrict__ kern) {
    __shared__ float w1[H_][ST_];
    __shared__ float sc[H_], bi[H_];
    __shared__ float w2[K_][H_];
    int tid = threadIdx.x;
    for (int i = tid; i < H_ * ST_; i += 256) w1[i / ST_][i % ST_] = g_w1[i];
    if (tid < H_) {
        float s = gam[tid] * rsqrtf(var[tid] + 1e-5f);
        sc[tid] = s;
        bi[tid] = bet[tid] - mean[tid] * s;
    }
    for (int i = tid; i < K_ * H_; i += 256) w2[i / H_][i % H_] = g_w2[i];
    __syncthreads();
    int row = blockIdx.x * 256 + tid;  // n*C + c
    const float* p = st + (size_t)row * ST_;
    float s[ST_];
#pragma unroll
    for (int i = 0; i < ST_; ++i) s[i] = p[i];
    float lg0 = 0.f, lg1 = 0.f, lg2 = 0.f;
    for (int j = 0; j < H_; ++j) {
        float h = 0.f;
#pragma unroll
        for (int i = 0; i < ST_; ++i) h = fmaf(w1[j][i], s[i], h);
        h = fmaxf(fmaf(h, sc[j], bi[j]), 0.f);
        lg0 = fmaf(w2[0][j], h, lg0);
        lg1 = fmaf(w2[1][j], h, lg1);
        lg2 = fmaf(w2[2][j], h, lg2);
    }
    float m = fmaxf(lg0, fmaxf(lg1, lg2));
    float e0 = __expf(lg0 - m), e1 = __expf(lg1 - m), e2 = __expf(lg2 - m);
    float inv = 1.f / (e0 + e1 + e2);
    float4 o = make_float4(e0 * inv, e1 * inv, e2 * inv, 0.f);
    *(float4*)(kern + (size_t)row * 4) = o;
}

// ---------------- P1: transpose lt [n][c][t] fp32 -> ltT [n][t+1][c] bf16
__global__ __launch_bounds__(256) void k_transpose(
    const float* __restrict__ lt, ushort_t* __restrict__ ltT) {
    __shared__ float tile[32][33];
    int tt0 = blockIdx.x * 32;
    int cc  = blockIdx.y * 32;
    int n   = blockIdx.z;
    const float* src = lt + ((size_t)n * C_ + cc) * LT_;
    int tx = threadIdx.x & 31, ty = threadIdx.x >> 5;  // ty 0..7
#pragma unroll
    for (int i = 0; i < 4; ++i) {
        int c = ty + i * 8;
        int t = tt0 + tx;
        tile[c][tx] = (t < LT_) ? src[(size_t)c * LT_ + t] : 0.f;
    }
    __syncthreads();
    int cx  = (threadIdx.x & 15) * 2;   // c pair
    int tyw = threadIdx.x >> 4;         // 0..15
    unsigned int* dst = (unsigned int*)(ltT + (size_t)n * LTP_ * C_ + cc + cx);
#pragma unroll
    for (int i = 0; i < 2; ++i) {
        int tl = tyw + i * 16;
        int t = tt0 + tl;
        if (t < LT_) {
            unsigned int v = (unsigned int)f2bf(tile[cx][tl]) |
                             ((unsigned int)f2bf(tile[cx + 1][tl]) << 16);
            dst[(size_t)(t + 1) * (C_ / 2)] = v;
        }
    }
}

// ---------------- P2: repack l_w1 [cb][c][k] -> w1b[k][cb][c] bf16
// (also zeroes ltT's two pad rows: folds the old k_zero launch in)
__global__ __launch_bounds__(256) void k_w1(
    const float* __restrict__ l_w1, ushort_t* __restrict__ w1b,
    ushort_t* __restrict__ ltT) {
    int i = blockIdx.x * 256 + threadIdx.x;  // over CB*C
    float a = l_w1[(size_t)i * 3 + 0];
    float b = l_w1[(size_t)i * 3 + 1];
    float c = l_w1[(size_t)i * 3 + 2];
    w1b[0 * (size_t)CB_ * C_ + i] = f2bf(a);
    w1b[1 * (size_t)CB_ * C_ + i] = f2bf(b);
    w1b[2 * (size_t)CB_ * C_ + i] = f2bf(c);
    if (i < N_ * C_) {
        int n = i >> 11, cc = i & (C_ - 1);
        size_t base = (size_t)n * LTP_ * C_;
        ltT[base + cc] = 0;
        ltT[base + (size_t)(LTP_ - 1) * C_ + cc] = 0;
    }
}

// ---------------- P3: convert l_w2 [c][cb] -> bf16
__global__ __launch_bounds__(256) void k_w2(
    const float* __restrict__ l_w2, ushort_t* __restrict__ w2b) {
    int i = blockIdx.x * 256 + threadIdx.x;  // over C*CB
    w2b[i] = f2bf(l_w2[i]);
}

// ---------------- G1: X[n][t][cb] = ReLU(BN(sum_k W1k @ lt_shift_k)), bf16 out
// Round-3-proven structure (best of 3 tested schedules): 256x128 tile (254
// valid M rows), 8 waves (4M x 2N), 3-deep counted-vmcnt pipeline, monolithic
// MFMA body, XOR-swizzled LDS (linear DMA dest + pre-swizzled global source).
__global__ __launch_bounds__(512, 2) void k_gemm1(
    const ushort_t* __restrict__ ltT, const ushort_t* __restrict__ w1b,
    const float* __restrict__ bn_g, const float* __restrict__ bn_b,
    const float* __restrict__ bn_m, const float* __restrict__ bn_v,
    ushort_t* __restrict__ Xws) {
    __shared__ __align__(16) ushort_t Asm[3 * 256 * BK + 2 * BK];  // +2-row tap slack
    __shared__ __align__(16) ushort_t Bsm[3 * 384 * BK];
    const int tid = threadIdx.x;
    const int mseg = blockIdx.x;          // 0..63 = n*2 + tchunk
    const int n   = mseg >> 1;
    const int tm  = (mseg & 1) * TV1;     // 0 or 254 (padded-coord base row)
    const int cb0 = blockIdx.y * 128;
    const int lane = tid & 63, lrow = lane & 15, quad = lane >> 4;
    const int wv = tid >> 6;              // 0..7
    const int wvM = wv >> 1, wvN = wv & 1;

    const int srow = lane >> 2;
    const int csrc = (((lane & 3) ^ ((lane >> 3) & 3)) << 3);  // ushort offset
    const ushort_t* gA[2];
#pragma unroll
    for (int i = 0; i < 2; ++i) {
        int r = (2 * wv + i) * 16 + srow;                 // LDS row 0..255
        int gr = tm + r; gr = gr < LTP_ - 1 ? gr : LTP_ - 1;  // clamp to zero pad row
        gA[i] = ltT + ((size_t)n * LTP_ + gr) * C_ + csrc;
    }
    const ushort_t* gB[3];
#pragma unroll
    for (int j = 0; j < 3; ++j) {
        int rB = (3 * wv + j) * 16 + srow;                // LDS row 0..383 = tap*128+cbl
        gB[j] = w1b + ((size_t)((rB >> 7) * CB_ + cb0 + (rB & 127))) * C_ + csrc;
    }
    const int sB = lrow * BK + ((quad ^ ((lrow >> 1) & 3)) << 3);
    int sA[3];
#pragma unroll
    for (int k = 0; k < 3; ++k)
        sA[k] = (lrow + k) * BK + ((quad ^ (((lrow + k) >> 1) & 3)) << 3);

    f32x4 acc[4][4];
#pragma unroll
    for (int i = 0; i < 4; ++i)
#pragma unroll
        for (int j = 0; j < 4; ++j) acc[i][j] = (f32x4){0.f, 0.f, 0.f, 0.f};

#define STAGE1(buf)                                                         \
    {                                                                       \
        ushort_t* ad = Asm + (buf) * (256 * BK) + (2 * wv) * (16 * BK);     \
        gload16(gA[0], ad);                                                 \
        gload16(gA[1], ad + 16 * BK);                                       \
        gA[0] += BK; gA[1] += BK;                                           \
        ushort_t* bd = Bsm + (buf) * (384 * BK) + (3 * wv) * (16 * BK);     \
        gload16(gB[0], bd);                                                 \
        gload16(gB[1], bd + 16 * BK);                                       \
        gload16(gB[2], bd + 32 * BK);                                       \
        gB[0] += BK; gB[1] += BK; gB[2] += BK;                              \
    }

    STAGE1(0);
    STAGE1(1);
    int cur = 0, pre = 2;
    for (int s = 0; s < C_ / BK; ++s) {
        if (s < C_ / BK - 1) asm volatile("s_waitcnt vmcnt(5)" ::: "memory");
        else                 asm volatile("s_waitcnt vmcnt(0)" ::: "memory");
        __builtin_amdgcn_sched_barrier(0);
        __builtin_amdgcn_s_barrier();
        __builtin_amdgcn_sched_barrier(0);
        if (s < C_ / BK - 2) {
            STAGE1(pre);
            pre = (pre == 2) ? 0 : pre + 1;
        }
        const ushort_t* Ab = Asm + cur * (256 * BK) + wvM * (64 * BK);
        const ushort_t* Bb = Bsm + cur * (384 * BK) + wvN * (64 * BK) + sB;
        bf16x8 bfr[3][4];
#pragma unroll
        for (int k = 0; k < 3; ++k)
#pragma unroll
            for (int nf = 0; nf < 4; ++nf)
                bfr[k][nf] = *(const bf16x8*)(Bb + k * (128 * BK) + nf * (16 * BK));
        __builtin_amdgcn_s_setprio(1);
#pragma unroll
        for (int mf = 0; mf < 4; ++mf) {
            bf16x8 af[3];
#pragma unroll
            for (int k = 0; k < 3; ++k)
                af[k] = *(const bf16x8*)(Ab + sA[k] + mf * (16 * BK));
#pragma unroll
            for (int nf = 0; nf < 4; ++nf)
#pragma unroll
                for (int k = 0; k < 3; ++k)
                    acc[mf][nf] = __builtin_amdgcn_mfma_f32_16x16x32_bf16(af[k], bfr[k][nf], acc[mf][nf], 0, 0, 0);
        }
        __builtin_amdgcn_s_setprio(0);
        cur = (cur == 2) ? 0 : cur + 1;
    }
#undef STAGE1
    float sc[4], bo[4];
#pragma unroll
    for (int nf = 0; nf < 4; ++nf) {
        int cb = cb0 + wvN * 64 + nf * 16 + lrow;
        float s0 = bn_g[cb] * rsqrtf(bn_v[cb] + 1e-5f);
        sc[nf] = s0;
        bo[nf] = bn_b[cb] - bn_m[cb] * s0;
    }
#pragma unroll
    for (int mf = 0; mf < 4; ++mf) {
#pragma unroll
        for (int r = 0; r < 4; ++r) {
            int local = wvM * 64 + mf * 16 + quad * 4 + r;
            int t = tm + local;
            if (local < TV1 && t < LT_) {
#pragma unroll
                for (int nf = 0; nf < 4; ++nf) {
                    int cb = cb0 + wvN * 64 + nf * 16 + lrow;
                    float v = fmaxf(fmaf(acc[mf][nf][r], sc[nf], bo[nf]), 0.f);
                    Xws[((size_t)n * LT_ + t) * CB_ + cb] = f2bf(v);
                }
            }
        }
    }
}

// ---------------- G2 (FUSED FINAL): out[n][c][t] = sum_i kern[i]*(lt*sigmoid(W2@X))[t+i-1]
// M=c (128), N=128 flattened (n,t) cols, stride 126 (cols 0/127 = conv halos).
// Epilogue v2: stage nl=lt*sigmoid(acc) as bf16 in the (dead) K-loop LDS
// [128 j][NLD c], ONE barrier, then 3-tap conv via ds_read_b64 — replaces the
// 224-shuffle / 8-barrier neighbor exchange (round-6 bottleneck: 95us epilogue).
__global__ __launch_bounds__(256, 3) void k_gemm2(
    const ushort_t* __restrict__ Xws, const ushort_t* __restrict__ w2b,
    const float* __restrict__ lt, const float* __restrict__ kern,
    float* __restrict__ out) {
    __shared__ __align__(16) ushort_t smem[2 * 3 * 128 * BK];  // 48 KB
    ushort_t* const Asm = smem;
    ushort_t* const Bsm = smem + 3 * 128 * BK;
    ushort_t* const nlb = smem;            // epilogue reuse: [128][NLD] bf16, 33 KB
    const int tid = threadIdx.x;
    const int cm  = blockIdx.x * 128;
    const int fnBase = (int)blockIdx.y * JW - 1;  // col j -> flat row fnBase+j
    const int lane = tid & 63, lrow = lane & 15, quad = lane >> 4;
    const int wv = tid >> 6, wvM = wv & 1, wvN = wv >> 1;

    const int srow = lane >> 2;
    const int csrc = (((lane & 3) ^ ((lane >> 3) & 3)) << 3);
    const ushort_t* gA[2];
    const ushort_t* gB[2];
#pragma unroll
    for (int i = 0; i < 2; ++i) {
        int r = (2 * wv + i) * 16 + srow;
        gA[i] = w2b + (size_t)(cm + r) * CB_ + csrc;
        int fr = fnBase + r;                       // clamp halo/OOB rows (values
        fr = fr < 0 ? 0 : (fr > FNT - 1 ? FNT - 1 : fr);  // only used where masked)
        gB[i] = Xws + (size_t)fr * CB_ + csrc;
    }
    const int sOff = lrow * BK + ((quad ^ ((lrow >> 1) & 3)) << 3);

    f32x4 acc[4][4];
#pragma unroll
    for (int i = 0; i < 4; ++i)
#pragma unroll
        for (int j = 0; j < 4; ++j) acc[i][j] = (f32x4){0.f, 0.f, 0.f, 0.f};

#define STAGE2(buf)                                                         \
    {                                                                       \
        ushort_t* ad = Asm + (buf) * (128 * BK) + (2 * wv) * (16 * BK);     \
        ushort_t* bd = Bsm + (buf) * (128 * BK) + (2 * wv) * (16 * BK);     \
        gload16(gA[0], ad);                                                 \
        gload16(gA[1], ad + 16 * BK);                                       \
        gload16(gB[0], bd);                                                 \
        gload16(gB[1], bd + 16 * BK);                                       \
        gA[0] += BK; gA[1] += BK; gB[0] += BK; gB[1] += BK;                 \
    }

    STAGE2(0);
    STAGE2(1);
    int cur = 0, pre = 2;
    for (int s = 0; s < CB_ / BK; ++s) {
        if (s < CB_ / BK - 1) asm volatile("s_waitcnt vmcnt(4)" ::: "memory");
        else                  asm volatile("s_waitcnt vmcnt(0)" ::: "memory");
        __builtin_amdgcn_sched_barrier(0);
        __builtin_amdgcn_s_barrier();
        __builtin_amdgcn_sched_barrier(0);
        if (s < CB_ / BK - 2) {
            STAGE2(pre);
            pre = (pre == 2) ? 0 : pre + 1;
        }
        const ushort_t* Ab = Asm + cur * (128 * BK) + wvM * (64 * BK) + sOff;
        const ushort_t* Bb = Bsm + cur * (128 * BK) + wvN * (64 * BK) + sOff;
        bf16x8 af[4], bfm[4];
#pragma unroll
        for (int mf = 0; mf < 4; ++mf)
            af[mf] = *(const bf16x8*)(Ab + mf * (16 * BK));
#pragma unroll
        for (int nf = 0; nf < 4; ++nf)
            bfm[nf] = *(const bf16x8*)(Bb + nf * (16 * BK));
        __builtin_amdgcn_s_setprio(1);
#pragma unroll
        for (int mf = 0; mf < 4; ++mf)
#pragma unroll
            for (int nf = 0; nf < 4; ++nf)
                acc[mf][nf] = __builtin_amdgcn_mfma_f32_16x16x32_bf16(af[mf], bfm[nf], acc[mf][nf], 0, 0, 0);
        __builtin_amdgcn_s_setprio(0);
        cur = (cur == 2) ? 0 : cur + 1;
    }
#undef STAGE2
    // ---- epilogue v2 ----
    __syncthreads();   // WAR: all waves done reading K-loop LDS before nl overwrite
    // phase 1: nl = bf16(lt * sigmoid(acc)) -> nlb[j][c], packed 4c per write
#pragma unroll
    for (int mf = 0; mf < 4; ++mf) {
        int cl = wvM * 64 + mf * 16 + quad * 4;
#pragma unroll
        for (int nf = 0; nf < 4; ++nf) {
            int j  = wvN * 64 + nf * 16 + lrow;
            int fn = fnBase + j;
            int fnc = fn < 0 ? 0 : (fn > FNT - 1 ? FNT - 1 : fn);
            int nn = fnc / LT_, t = fnc - nn * LT_;
            const float* ltp = lt + ((size_t)nn * C_ + cm + cl) * LT_ + t;
            unsigned int u01, u23;
            {
                float g0 = 1.f / (1.f + __expf(-acc[mf][nf][0]));
                float g1 = 1.f / (1.f + __expf(-acc[mf][nf][1]));
                float g2 = 1.f / (1.f + __expf(-acc[mf][nf][2]));
                float g3 = 1.f / (1.f + __expf(-acc[mf][nf][3]));
                unsigned short b0 = f2bf(ltp[0] * g0);
                unsigned short b1 = f2bf(ltp[(size_t)LT_] * g1);
                unsigned short b2 = f2bf(ltp[(size_t)2 * LT_] * g2);
                unsigned short b3 = f2bf(ltp[(size_t)3 * LT_] * g3);
                u01 = (unsigned)b0 | ((unsigned)b1 << 16);
                u23 = (unsigned)b2 | ((unsigned)b3 << 16);
            }
            *(uint2*)&nlb[j * NLD + cl] = make_uint2(u01, u23);
        }
    }
    __syncthreads();
    // phase 2: 3-tap conv from nlb, masked store
#pragma unroll
    for (int mf = 0; mf < 4; ++mf) {
        int cl = wvM * 64 + mf * 16 + quad * 4;
#pragma unroll
        for (int nf = 0; nf < 4; ++nf) {
            int j  = wvN * 64 + nf * 16 + lrow;
            int fn = fnBase + j;
            if (j >= 1 && j <= JW && fn < FNT) {
                int nn = fn / LT_, t = fn - nn * LT_;
                uint2 va = *(const uint2*)&nlb[(j - 1) * NLD + cl];
                uint2 vb = *(const uint2*)&nlb[j * NLD + cl];
                uint2 vc = *(const uint2*)&nlb[(j + 1) * NLD + cl];
                float lft[4] = {bf2f((unsigned short)(va.x & 0xffffu)),
                                bf2f((unsigned short)(va.x >> 16)),
                                bf2f((unsigned short)(va.y & 0xffffu)),
                                bf2f((unsigned short)(va.y >> 16))};
                float ctr[4] = {bf2f((unsigned short)(vb.x & 0xffffu)),
                                bf2f((unsigned short)(vb.x >> 16)),
                                bf2f((unsigned short)(vb.y & 0xffffu)),
                                bf2f((unsigned short)(vb.y >> 16))};
                float rgt[4] = {bf2f((unsigned short)(vc.x & 0xffffu)),
                                bf2f((unsigned short)(vc.x >> 16)),
                                bf2f((unsigned short)(vc.y & 0xffffu)),
                                bf2f((unsigned short)(vc.y >> 16))};
#pragma unroll
                for (int r = 0; r < 4; ++r) {
                    int c = cm + cl + r;
                    float4 kv = *(const float4*)(kern + ((size_t)nn * C_ + c) * 4);
                    float o = kv.y * ctr[r];
                    if (t > 0)       o += kv.x * lft[r];
                    if (t < LT_ - 1) o += kv.z * rgt[r];
                    out[((size_t)nn * C_ + c) * LT_ + t] = o;
                }
            }
        }
    }
}

extern "C" void kernel_launch(void* const* d_in, const int* in_sizes, int n_in,
                              void* d_out, int out_size, void* d_ws, size_t ws_size,
                              hipStream_t stream) {
    const float* st   = (const float*)d_in[0];
    const float* lt   = (const float*)d_in[1];
    const float* g_w1 = (const float*)d_in[2];
    const float* g_bg = (const float*)d_in[3];
    const float* g_bb = (const float*)d_in[4];
    const float* g_bm = (const float*)d_in[5];
    const float* g_bv = (const float*)d_in[6];
    const float* g_w2 = (const float*)d_in[7];
    const float* l_w1 = (const float*)d_in[8];
    const float* l_bg = (const float*)d_in[9];
    const float* l_bb = (const float*)d_in[10];
    const float* l_bm = (const float*)d_in[11];
    const float* l_bv = (const float*)d_in[12];
    const float* l_w2 = (const float*)d_in[13];
    float* out = (float*)d_out;

    char* ws = (char*)d_ws;
    // workspace layout (bytes)
    float*    kern = (float*)(ws + 0);                    // 1,048,576
    ushort_t* w1b  = (ushort_t*)(ws + 1048576);           // 6,291,456
    ushort_t* w2b  = (ushort_t*)(ws + 7340032);           // 2,097,152
    ushort_t* Xws  = (ushort_t*)(ws + 9437184);           // 13,107,200
    ushort_t* ltT  = (ushort_t*)(ws + 22544384);          // 52,690,944

    k_global<<<dim3((N_ * C_) / 256), dim3(256), 0, stream>>>(
        st, g_w1, g_bg, g_bb, g_bm, g_bv, g_w2, kern);
    k_w1<<<dim3((CB_ * C_) / 256), dim3(256), 0, stream>>>(l_w1, w1b, ltT);
    k_w2<<<dim3((C_ * CB_) / 256), dim3(256), 0, stream>>>(l_w2, w2b);
    k_transpose<<<dim3(13, C_ / 32, N_), dim3(256), 0, stream>>>(lt, ltT);
    k_gemm1<<<dim3(64, 4), dim3(512), 0, stream>>>(
        ltT, w1b, l_bg, l_bb, l_bm, l_bv, Xws);
    k_gemm2<<<dim3(C_ / 128, (FNT + JW - 1) / JW), dim3(256), 0, stream>>>(
        Xws, w2b, lt, kern, out);
}

// Round 8
// 421.622 us; speedup vs baseline: 1.0791x; 1.0506x over previous
//
#include <hip/hip_runtime.h>
#include <hip/hip_bf16.h>

#define N_   32
#define C_   2048
#define ST_  16
#define H_   64      // ST*ALPHA
#define K_   3
#define CB_  512
#define LT_  400
#define LTP_ 402     // padded t rows (1 zero row each side)
#define BK   32      // K-step (bf16 elements) -> 64B LDS rows
#define TV1  254     // gemm1 valid rows per 256-row M tile (2-row tap halo)
#define FNT  12800   // N_*LT_ flattened (n,t) rows
#define JW   126     // gemm2 valid cols per 128-col N tile (2-col conv halo)
#define NLD  132     // nl LDS row stride (bf16): pad 4 keeps 8B align + kills conflicts

using bf16x8 = __attribute__((ext_vector_type(8))) __bf16;
using f32x4  = __attribute__((ext_vector_type(4))) float;
typedef unsigned short ushort_t;

__device__ __forceinline__ unsigned short f2bf(float f) {
    unsigned int u = __float_as_uint(f);
    u = (u + 0x7fffu + ((u >> 16) & 1u)) >> 16;
    return (unsigned short)u;
}
__device__ __forceinline__ float bf2f(unsigned short h) {
    return __uint_as_float(((unsigned int)h) << 16);
}
// async global->LDS DMA, 16B/lane. Dest = wave-uniform base + lane*16 (linear).
__device__ __forceinline__ void gload16(const ushort_t* g, ushort_t* l) {
    __builtin_amdgcn_global_load_lds(
        (const __attribute__((address_space(1))) unsigned int*)g,
        (__attribute__((address_space(3))) unsigned int*)l, 16, 0, 0);
}

// ---------------- P0: global branch -> per-(n,c) softmax kernel [NC,4] fp32
__global__ __launch_bounds__(256) void k_global(
    const float* __restrict__ st, const float* __restrict__ g_w1,
    const float* __restrict__ gam, const float* __restrict__ bet,
    const float* __restrict__ mean, const float* __restrict__ var,
    const float* __restrict__ g_w2, float* __restrict__ kern) {
    __shared__ float w1[H_][ST_];
    __shared__ float sc[H_], bi[H_];
    __shared__ float w2[K_][H_];
    int tid = threadIdx.x;
    for (int i = tid; i < H_ * ST_; i += 256) w1[i / ST_][i % ST_] = g_w1[i];
    if (tid < H_) {
        float s = gam[tid] * rsqrtf(var[tid] + 1e-5f);
        sc[tid] = s;
        bi[tid] = bet[tid] - mean[tid] * s;
    }
    for (int i = tid; i < K_ * H_; i += 256) w2[i / H_][i % H_] = g_w2[i];
    __syncthreads();
    int row = blockIdx.x * 256 + tid;  // n*C + c
    const float* p = st + (size_t)row * ST_;
    float s[ST_];
#pragma unroll
    for (int i = 0; i < ST_; ++i) s[i] = p[i];
    float lg0 = 0.f, lg1 = 0.f, lg2 = 0.f;
    for (int j = 0; j < H_; ++j) {
        float h = 0.f;
#pragma unroll
        for (int i = 0; i < ST_; ++i) h = fmaf(w1[j][i], s[i], h);
        h = fmaxf(fmaf(h, sc[j], bi[j]), 0.f);
        lg0 = fmaf(w2[0][j], h, lg0);
        lg1 = fmaf(w2[1][j], h, lg1);
        lg2 = fmaf(w2[2][j], h, lg2);
    }
    float m = fmaxf(lg0, fmaxf(lg1, lg2));
    float e0 = __expf(lg0 - m), e1 = __expf(lg1 - m), e2 = __expf(lg2 - m);
    float inv = 1.f / (e0 + e1 + e2);
    float4 o = make_float4(e0 * inv, e1 * inv, e2 * inv, 0.f);
    *(float4*)(kern + (size_t)row * 4) = o;
}

// ---------------- P1: transpose lt [n][c][t] fp32 -> ltT [n][t+1][c] bf16
// v2: 64t x 32c tile, float4 reads, uint2 (4-channel) writes. Half the blocks,
// 4x wider global ops vs v1.
__global__ __launch_bounds__(256) void k_transpose(
    const float* __restrict__ lt, ushort_t* __restrict__ ltT) {
    __shared__ float tile[32][65];   // [c][t], pad breaks bank conflicts
    int tt0 = blockIdx.x * 64;
    int cc  = blockIdx.y * 32;
    int n   = blockIdx.z;
    const float* src = lt + ((size_t)n * C_ + cc) * LT_;
    int c  = threadIdx.x >> 3;       // 0..31
    int tq = threadIdx.x & 7;        // 0..7
#pragma unroll
    for (int i = 0; i < 2; ++i) {
        int tl = tq * 4 + i * 32;
        int t = tt0 + tl;
        float4 v = make_float4(0.f, 0.f, 0.f, 0.f);
        if (t < LT_) v = *(const float4*)(src + (size_t)c * LT_ + t);  // LT_%4==0
        *(float4*)&tile[c][tl] = v;
    }
    __syncthreads();
    int cq = (threadIdx.x & 7) * 4;  // c offset 0,4,..28
    int tw = threadIdx.x >> 3;       // 0..31
    ushort_t* dstb = ltT + (size_t)n * LTP_ * C_ + cc + cq;
#pragma unroll
    for (int i = 0; i < 2; ++i) {
        int tl = tw + i * 32;
        int t = tt0 + tl;
        if (t < LT_) {
            unsigned int u01 = (unsigned)f2bf(tile[cq + 0][tl]) |
                               ((unsigned)f2bf(tile[cq + 1][tl]) << 16);
            unsigned int u23 = (unsigned)f2bf(tile[cq + 2][tl]) |
                               ((unsigned)f2bf(tile[cq + 3][tl]) << 16);
            *(uint2*)(dstb + (size_t)(t + 1) * C_) = make_uint2(u01, u23);
        }
    }
}

// ---------------- P2: merged prep — w1 repack + w2 convert + ltT pad-row zero
__global__ __launch_bounds__(256) void k_prep(
    const float* __restrict__ l_w1, const float* __restrict__ l_w2,
    ushort_t* __restrict__ w1b, ushort_t* __restrict__ w2b,
    ushort_t* __restrict__ ltT) {
    int i = blockIdx.x * 256 + threadIdx.x;  // over CB_*C_ = C_*CB_
    float a = l_w1[(size_t)i * 3 + 0];
    float b = l_w1[(size_t)i * 3 + 1];
    float c = l_w1[(size_t)i * 3 + 2];
    w1b[0 * (size_t)CB_ * C_ + i] = f2bf(a);
    w1b[1 * (size_t)CB_ * C_ + i] = f2bf(b);
    w1b[2 * (size_t)CB_ * C_ + i] = f2bf(c);
    w2b[i] = f2bf(l_w2[i]);
    if (i < N_ * C_) {
        int n = i >> 11, cc = i & (C_ - 1);
        size_t base = (size_t)n * LTP_ * C_;
        ltT[base + cc] = 0;
        ltT[base + (size_t)(LTP_ - 1) * C_ + cc] = 0;
    }
}

// ---------------- G1: X[n][t][cb] = ReLU(BN(sum_k W1k @ lt_shift_k)), bf16 out
// Round-3-proven structure: 256x128 tile (254 valid M rows), 8 waves (4M x 2N),
// 3-deep counted-vmcnt pipeline, monolithic MFMA body, XOR-swizzled LDS.
__global__ __launch_bounds__(512, 2) void k_gemm1(
    const ushort_t* __restrict__ ltT, const ushort_t* __restrict__ w1b,
    const float* __restrict__ bn_g, const float* __restrict__ bn_b,
    const float* __restrict__ bn_m, const float* __restrict__ bn_v,
    ushort_t* __restrict__ Xws) {
    __shared__ __align__(16) ushort_t Asm[3 * 256 * BK + 2 * BK];  // +2-row tap slack
    __shared__ __align__(16) ushort_t Bsm[3 * 384 * BK];
    const int tid = threadIdx.x;
    const int mseg = blockIdx.x;          // 0..63 = n*2 + tchunk
    const int n   = mseg >> 1;
    const int tm  = (mseg & 1) * TV1;     // 0 or 254 (padded-coord base row)
    const int cb0 = blockIdx.y * 128;
    const int lane = tid & 63, lrow = lane & 15, quad = lane >> 4;
    const int wv = tid >> 6;              // 0..7
    const int wvM = wv >> 1, wvN = wv & 1;

    const int srow = lane >> 2;
    const int csrc = (((lane & 3) ^ ((lane >> 3) & 3)) << 3);  // ushort offset
    const ushort_t* gA[2];
#pragma unroll
    for (int i = 0; i < 2; ++i) {
        int r = (2 * wv + i) * 16 + srow;                 // LDS row 0..255
        int gr = tm + r; gr = gr < LTP_ - 1 ? gr : LTP_ - 1;  // clamp to zero pad row
        gA[i] = ltT + ((size_t)n * LTP_ + gr) * C_ + csrc;
    }
    const ushort_t* gB[3];
#pragma unroll
    for (int j = 0; j < 3; ++j) {
        int rB = (3 * wv + j) * 16 + srow;                // LDS row 0..383 = tap*128+cbl
        gB[j] = w1b + ((size_t)((rB >> 7) * CB_ + cb0 + (rB & 127))) * C_ + csrc;
    }
    const int sB = lrow * BK + ((quad ^ ((lrow >> 1) & 3)) << 3);
    int sA[3];
#pragma unroll
    for (int k = 0; k < 3; ++k)
        sA[k] = (lrow + k) * BK + ((quad ^ (((lrow + k) >> 1) & 3)) << 3);

    f32x4 acc[4][4];
#pragma unroll
    for (int i = 0; i < 4; ++i)
#pragma unroll
        for (int j = 0; j < 4; ++j) acc[i][j] = (f32x4){0.f, 0.f, 0.f, 0.f};

#define STAGE1(buf)                                                         \
    {                                                                       \
        ushort_t* ad = Asm + (buf) * (256 * BK) + (2 * wv) * (16 * BK);     \
        gload16(gA[0], ad);                                                 \
        gload16(gA[1], ad + 16 * BK);                                       \
        gA[0] += BK; gA[1] += BK;                                           \
        ushort_t* bd = Bsm + (buf) * (384 * BK) + (3 * wv) * (16 * BK);     \
        gload16(gB[0], bd);                                                 \
        gload16(gB[1], bd + 16 * BK);                                       \
        gload16(gB[2], bd + 32 * BK);                                       \
        gB[0] += BK; gB[1] += BK; gB[2] += BK;                              \
    }

    STAGE1(0);
    STAGE1(1);
    int cur = 0, pre = 2;
    for (int s = 0; s < C_ / BK; ++s) {
        if (s < C_ / BK - 1) asm volatile("s_waitcnt vmcnt(5)" ::: "memory");
        else                 asm volatile("s_waitcnt vmcnt(0)" ::: "memory");
        __builtin_amdgcn_sched_barrier(0);
        __builtin_amdgcn_s_barrier();
        __builtin_amdgcn_sched_barrier(0);
        if (s < C_ / BK - 2) {
            STAGE1(pre);
            pre = (pre == 2) ? 0 : pre + 1;
        }
        const ushort_t* Ab = Asm + cur * (256 * BK) + wvM * (64 * BK);
        const ushort_t* Bb = Bsm + cur * (384 * BK) + wvN * (64 * BK) + sB;
        bf16x8 bfr[3][4];
#pragma unroll
        for (int k = 0; k < 3; ++k)
#pragma unroll
            for (int nf = 0; nf < 4; ++nf)
                bfr[k][nf] = *(const bf16x8*)(Bb + k * (128 * BK) + nf * (16 * BK));
        __builtin_amdgcn_s_setprio(1);
#pragma unroll
        for (int mf = 0; mf < 4; ++mf) {
            bf16x8 af[3];
#pragma unroll
            for (int k = 0; k < 3; ++k)
                af[k] = *(const bf16x8*)(Ab + sA[k] + mf * (16 * BK));
#pragma unroll
            for (int nf = 0; nf < 4; ++nf)
#pragma unroll
                for (int k = 0; k < 3; ++k)
                    acc[mf][nf] = __builtin_amdgcn_mfma_f32_16x16x32_bf16(af[k], bfr[k][nf], acc[mf][nf], 0, 0, 0);
        }
        __builtin_amdgcn_s_setprio(0);
        cur = (cur == 2) ? 0 : cur + 1;
    }
#undef STAGE1
    float sc[4], bo[4];
#pragma unroll
    for (int nf = 0; nf < 4; ++nf) {
        int cb = cb0 + wvN * 64 + nf * 16 + lrow;
        float s0 = bn_g[cb] * rsqrtf(bn_v[cb] + 1e-5f);
        sc[nf] = s0;
        bo[nf] = bn_b[cb] - bn_m[cb] * s0;
    }
#pragma unroll
    for (int mf = 0; mf < 4; ++mf) {
#pragma unroll
        for (int r = 0; r < 4; ++r) {
            int local = wvM * 64 + mf * 16 + quad * 4 + r;
            int t = tm + local;
            if (local < TV1 && t < LT_) {
#pragma unroll
                for (int nf = 0; nf < 4; ++nf) {
                    int cb = cb0 + wvN * 64 + nf * 16 + lrow;
                    float v = fmaxf(fmaf(acc[mf][nf][r], sc[nf], bo[nf]), 0.f);
                    Xws[((size_t)n * LT_ + t) * CB_ + cb] = f2bf(v);
                }
            }
        }
    }
}

// ---------------- G2 (FUSED FINAL): out[n][c][t] = sum_i kern[i]*(lt*sigmoid(W2@X))[t+i-1]
// v3: 2-buffer staging (round-1-proven __syncthreads pipeline) shrinks LDS so
// the block fits 4x/CU (16 waves) — gemm2 is BW/latency-bound, so TLP is the
// lever (was 3 blocks/CU, 2.1 serial passes of the 1632-block grid).
// Epilogue: nl staged as bf16 in the (dead) staging LDS, one barrier, 3-tap
// conv via ds_read_b64.
__global__ __launch_bounds__(256, 4) void k_gemm2(
    const ushort_t* __restrict__ Xws, const ushort_t* __restrict__ w2b,
    const float* __restrict__ lt, const float* __restrict__ kern,
    float* __restrict__ out) {
    __shared__ __align__(16) ushort_t smem[128 * NLD];  // 33.8 KB: 32KB staging / nlb
    ushort_t* const nlb = smem;        // epilogue: [128 j][NLD c] bf16
    const int tid = threadIdx.x;
    const int cm  = blockIdx.x * 128;
    const int fnBase = (int)blockIdx.y * JW - 1;  // col j -> flat row fnBase+j
    const int lane = tid & 63, lrow = lane & 15, quad = lane >> 4;
    const int wv = tid >> 6, wvM = wv & 1, wvN = wv >> 1;

    const int srow = lane >> 2;
    const int csrc = (((lane & 3) ^ ((lane >> 3) & 3)) << 3);
    const ushort_t* gA[2];
    const ushort_t* gB[2];
#pragma unroll
    for (int i = 0; i < 2; ++i) {
        int r = (2 * wv + i) * 16 + srow;
        gA[i] = w2b + (size_t)(cm + r) * CB_ + csrc;
        int fr = fnBase + r;                       // clamp halo/OOB rows (values
        fr = fr < 0 ? 0 : (fr > FNT - 1 ? FNT - 1 : fr);  // only used where masked)
        gB[i] = Xws + (size_t)fr * CB_ + csrc;
    }
    const int sOff = lrow * BK + ((quad ^ ((lrow >> 1) & 3)) << 3);

    f32x4 acc[4][4];
#pragma unroll
    for (int i = 0; i < 4; ++i)
#pragma unroll
        for (int j = 0; j < 4; ++j) acc[i][j] = (f32x4){0.f, 0.f, 0.f, 0.f};

    // staging layout: A0 @0, A1 @4096, B0 @8192, B1 @12288 (ushorts)
#define STAGE2(buf)                                                         \
    {                                                                       \
        ushort_t* ad = smem + (buf) * (128 * BK) + (2 * wv) * (16 * BK);    \
        ushort_t* bd = smem + 8192 + (buf) * (128 * BK) + (2 * wv) * (16 * BK); \
        gload16(gA[0], ad);                                                 \
        gload16(gA[1], ad + 16 * BK);                                       \
        gload16(gB[0], bd);                                                 \
        gload16(gB[1], bd + 16 * BK);                                       \
        gA[0] += BK; gA[1] += BK; gB[0] += BK; gB[1] += BK;                 \
    }

    STAGE2(0);
    int cur = 0;
    for (int s = 0; s < CB_ / BK; ++s) {
        __syncthreads();                 // drains DMA of buf cur (vmcnt 0 implicit)
        if (s + 1 < CB_ / BK) STAGE2(cur ^ 1);
        const ushort_t* Ab = smem + cur * (128 * BK) + wvM * (64 * BK) + sOff;
        const ushort_t* Bb = smem + 8192 + cur * (128 * BK) + wvN * (64 * BK) + sOff;
        bf16x8 af[4], bfm[4];
#pragma unroll
        for (int mf = 0; mf < 4; ++mf)
            af[mf] = *(const bf16x8*)(Ab + mf * (16 * BK));
#pragma unroll
        for (int nf = 0; nf < 4; ++nf)
            bfm[nf] = *(const bf16x8*)(Bb + nf * (16 * BK));
        __builtin_amdgcn_s_setprio(1);
#pragma unroll
        for (int mf = 0; mf < 4; ++mf)
#pragma unroll
            for (int nf = 0; nf < 4; ++nf)
                acc[mf][nf] = __builtin_amdgcn_mfma_f32_16x16x32_bf16(af[mf], bfm[nf], acc[mf][nf], 0, 0, 0);
        __builtin_amdgcn_s_setprio(0);
        cur ^= 1;
    }
#undef STAGE2
    // ---- epilogue ----
    __syncthreads();   // WAR: all waves done reading staging LDS before nl overwrite
#pragma unroll
    for (int mf = 0; mf < 4; ++mf) {
        int cl = wvM * 64 + mf * 16 + quad * 4;
#pragma unroll
        for (int nf = 0; nf < 4; ++nf) {
            int j  = wvN * 64 + nf * 16 + lrow;
            int fn = fnBase + j;
            int fnc = fn < 0 ? 0 : (fn > FNT - 1 ? FNT - 1 : fn);
            int nn = fnc / LT_, t = fnc - nn * LT_;
            const float* ltp = lt + ((size_t)nn * C_ + cm + cl) * LT_ + t;
            float g0 = 1.f / (1.f + __expf(-acc[mf][nf][0]));
            float g1 = 1.f / (1.f + __expf(-acc[mf][nf][1]));
            float g2 = 1.f / (1.f + __expf(-acc[mf][nf][2]));
            float g3 = 1.f / (1.f + __expf(-acc[mf][nf][3]));
            unsigned short b0 = f2bf(ltp[0] * g0);
            unsigned short b1 = f2bf(ltp[(size_t)LT_] * g1);
            unsigned short b2 = f2bf(ltp[(size_t)2 * LT_] * g2);
            unsigned short b3 = f2bf(ltp[(size_t)3 * LT_] * g3);
            unsigned int u01 = (unsigned)b0 | ((unsigned)b1 << 16);
            unsigned int u23 = (unsigned)b2 | ((unsigned)b3 << 16);
            *(uint2*)&nlb[j * NLD + cl] = make_uint2(u01, u23);
        }
    }
    __syncthreads();
#pragma unroll
    for (int mf = 0; mf < 4; ++mf) {
        int cl = wvM * 64 + mf * 16 + quad * 4;
#pragma unroll
        for (int nf = 0; nf < 4; ++nf) {
            int j  = wvN * 64 + nf * 16 + lrow;
            int fn = fnBase + j;
            if (j >= 1 && j <= JW && fn < FNT) {
                int nn = fn / LT_, t = fn - nn * LT_;
                uint2 va = *(const uint2*)&nlb[(j - 1) * NLD + cl];
                uint2 vb = *(const uint2*)&nlb[j * NLD + cl];
                uint2 vc = *(const uint2*)&nlb[(j + 1) * NLD + cl];
                float lft[4] = {bf2f((unsigned short)(va.x & 0xffffu)),
                                bf2f((unsigned short)(va.x >> 16)),
                                bf2f((unsigned short)(va.y & 0xffffu)),
                                bf2f((unsigned short)(va.y >> 16))};
                float ctr[4] = {bf2f((unsigned short)(vb.x & 0xffffu)),
                                bf2f((unsigned short)(vb.x >> 16)),
                                bf2f((unsigned short)(vb.y & 0xffffu)),
                                bf2f((unsigned short)(vb.y >> 16))};
                float rgt[4] = {bf2f((unsigned short)(vc.x & 0xffffu)),
                                bf2f((unsigned short)(vc.x >> 16)),
                                bf2f((unsigned short)(vc.y & 0xffffu)),
                                bf2f((unsigned short)(vc.y >> 16))};
#pragma unroll
                for (int r = 0; r < 4; ++r) {
                    int c = cm + cl + r;
                    float4 kv = *(const float4*)(kern + ((size_t)nn * C_ + c) * 4);
                    float o = kv.y * ctr[r];
                    if (t > 0)       o += kv.x * lft[r];
                    if (t < LT_ - 1) o += kv.z * rgt[r];
                    out[((size_t)nn * C_ + c) * LT_ + t] = o;
                }
            }
        }
    }
}

extern "C" void kernel_launch(void* const* d_in, const int* in_sizes, int n_in,
                              void* d_out, int out_size, void* d_ws, size_t ws_size,
                              hipStream_t stream) {
    const float* st   = (const float*)d_in[0];
    const float* lt   = (const float*)d_in[1];
    const float* g_w1 = (const float*)d_in[2];
    const float* g_bg = (const float*)d_in[3];
    const float* g_bb = (const float*)d_in[4];
    const float* g_bm = (const float*)d_in[5];
    const float* g_bv = (const float*)d_in[6];
    const float* g_w2 = (const float*)d_in[7];
    const float* l_w1 = (const float*)d_in[8];
    const float* l_bg = (const float*)d_in[9];
    const float* l_bb = (const float*)d_in[10];
    const float* l_bm = (const float*)d_in[11];
    const float* l_bv = (const float*)d_in[12];
    const float* l_w2 = (const float*)d_in[13];
    float* out = (float*)d_out;

    char* ws = (char*)d_ws;
    // workspace layout (bytes)
    float*    kern = (float*)(ws + 0);                    // 1,048,576
    ushort_t* w1b  = (ushort_t*)(ws + 1048576);           // 6,291,456
    ushort_t* w2b  = (ushort_t*)(ws + 7340032);           // 2,097,152
    ushort_t* Xws  = (ushort_t*)(ws + 9437184);           // 13,107,200
    ushort_t* ltT  = (ushort_t*)(ws + 22544384);          // 52,690,944

    k_global<<<dim3((N_ * C_) / 256), dim3(256), 0, stream>>>(
        st, g_w1, g_bg, g_bb, g_bm, g_bv, g_w2, kern);
    k_prep<<<dim3((CB_ * C_) / 256), dim3(256), 0, stream>>>(
        l_w1, l_w2, w1b, w2b, ltT);
    k_transpose<<<dim3(7, C_ / 32, N_), dim3(256), 0, stream>>>(lt, ltT);
    k_gemm1<<<dim3(64, 4), dim3(512), 0, stream>>>(
        ltT, w1b, l_bg, l_bb, l_bm, l_bv, Xws);
    k_gemm2<<<dim3(C_ / 128, (FNT + JW - 1) / JW), dim3(256), 0, stream>>>(
        Xws, w2b, lt, kern, out);
}